// Round 8
// baseline (347.198 us; speedup 1.0000x reference)
//
#include <hip/hip_runtime.h>

// Problem constants (from reference)
#define N_NODES 12500
#define N_EDGES 200000
#define DIM 32          // IN == OUT == ATTN == 32
#define N_REL 200
#define N_BASES 50

#define OUT_ELEMS   (N_NODES * DIM)
#define ZERO_BLOCKS 391

// Padded edge capacity: per-rel lists padded to multiples of 16.
// PE_MAX - N_EDGES = 3008 dummy slots exactly (per-rel pads + tail).
#define PE_MAX 203008

// Chunking shared by prep-hist and mega gate/scatter.
#define CPG 13                      // 64-edge groups per chunk
#define CHUNK (CPG * 64)            // 832
#define NGROUPS 3125                // 200000 / 64
#define NB_CHUNK 241                // ceil(3125/13); last chunk = 5 groups
#define NB_PAD 244                  // int4-aligned row stride (pads zeroed)

#define MEGA_BLK 256                // 1 block/CU -> all co-resident
#define EDGE_UNITS (PE_MAX / 64)    // 3172 wave-units of 64 slots
#define N_DUMMY_WRITERS (MEGA_BLK - NB_CHUNK)   // 15

#define HIST_BASE (N_REL + 1 + ZERO_BLOCKS)     // 592
#define PREP_BLOCKS (HIST_BASE + NB_CHUNK)      // 833

// ws layout (bytes):
//   [0, 409600)        bf16 relwT_bf[200][32][32]  TRANSPOSED: [r][o][i]
//   [409600, +8192)    bf16 aw_bf[32][128]
//   [417792, +2048)    bf16 slwT_bf[32][32]        (slw transposed)
//   [419840, +195200)  int  blockCountsT[N_REL][NB_PAD]
//   [615040, +195200)  int  blockBaseT[N_REL][NB_PAD]
//   [810240, +816)     int  offs[201]   (offs[200] = padded total)
//   [811056, +800)     int  tots[200]
//   [811856, +16)      int  flags[4]    {scanflag, bar, -, -} (prep zeroes)
//   [811872, +16*PE_MAX) int4 slot4[PE_MAX] {src, tgt(-1=dummy), a_bits, rel}
#define AWBF_OFF  (N_REL * 1024 * 2)
#define SLWT_OFF  (AWBF_OFF + 32 * 128 * 2)
#define BCT_OFF   (SLWT_OFF + 32 * 32 * 2)
#define BBT_OFF   (BCT_OFF + N_REL * NB_PAD * 4)
#define OFFS_OFF  (BBT_OFF + N_REL * NB_PAD * 4)
#define TOTS_OFF  (OFFS_OFF + 816)
#define FLAG_OFF  (TOTS_OFF + 800)
#define SLOT_OFF  (FLAG_OFF + 16)               // 811872, 16B-aligned

typedef __attribute__((ext_vector_type(8))) short short8;   // 8 bf16 (4 VGPRs)
typedef __attribute__((ext_vector_type(4))) float f32x4;    // MFMA acc

__device__ __forceinline__ unsigned short f2bf(float x) {
    union { float f; unsigned u; } v; v.f = x;
    unsigned r = (v.u + 0x7FFFu + ((v.u >> 16) & 1u)) >> 16;
    return (unsigned short)r;
}

__device__ __forceinline__ short8 cvt8(float4 a, float4 b) {
    short8 r;
    r[0] = (short)f2bf(a.x); r[1] = (short)f2bf(a.y);
    r[2] = (short)f2bf(a.z); r[3] = (short)f2bf(a.w);
    r[4] = (short)f2bf(b.x); r[5] = (short)f2bf(b.y);
    r[6] = (short)f2bf(b.z); r[7] = (short)f2bf(b.w);
    return r;
}

#define MFMA(A, B, C) __builtin_amdgcn_mfma_f32_16x16x32_bf16(A, B, C, 0, 0, 0)

// Dispatch 1 — prep: [0,200) rel_w basis -> bf16T; 200: Aw/slwT convert +
// zero sync flags + zero blockCountsT pad columns; [201,592) out zero-fill;
// [592,833) per-chunk LDS hist -> blockCountsT. Crossing the dispatch
// boundary gives the hist->scan ordering with no in-kernel sync.
__global__ __launch_bounds__(256) void prep_kernel(
    const float* __restrict__ weight,   // [50,32,32]
    const float* __restrict__ w_comp,   // [200,50]
    const float* __restrict__ Aw,       // [32,128]
    const float* __restrict__ slw,      // [32,32]
    const int*  __restrict__ rel,       // [E]
    unsigned short* __restrict__ relwT_bf,
    unsigned short* __restrict__ aw_bf,
    unsigned short* __restrict__ slwT_bf,
    int* __restrict__ blockCountsT,
    int* __restrict__ flags,
    float* __restrict__ out)
{
    int b = blockIdx.x, tid = threadIdx.x;
    if (b < N_REL) {
        __shared__ float wc[N_BASES];
        if (tid < N_BASES) wc[tid] = w_comp[b * N_BASES + tid];
        __syncthreads();
        const float* wp = weight + tid * 4;
        float4 acc = make_float4(0.f, 0.f, 0.f, 0.f);
        #pragma unroll 10
        for (int bb = 0; bb < N_BASES; bb++) {
            float4 w = *(const float4*)(wp + bb * 1024);
            float c = wc[bb];
            acc.x = fmaf(c, w.x, acc.x); acc.y = fmaf(c, w.y, acc.y);
            acc.z = fmaf(c, w.z, acc.z); acc.w = fmaf(c, w.w, acc.w);
        }
        // flat f = tid*4 + j over [i][o] (o fastest); write transposed [r][o][i]
        int i  = tid >> 3;
        int o0 = (tid * 4) & 31;
        unsigned short* dst = relwT_bf + b * 1024 + i;
        dst[(o0 + 0) * 32] = f2bf(acc.x);
        dst[(o0 + 1) * 32] = f2bf(acc.y);
        dst[(o0 + 2) * 32] = f2bf(acc.z);
        dst[(o0 + 3) * 32] = f2bf(acc.w);
    } else if (b == N_REL) {
        for (int x = tid; x < 32 * 128; x += 256) aw_bf[x] = f2bf(Aw[x]);
        for (int x = tid; x < 32 * 32; x += 256) {
            int i = x >> 5, j = x & 31;          // slw[i][j]
            slwT_bf[j * 32 + i] = f2bf(slw[x]);
        }
        if (tid < 4) flags[tid] = 0;
        // zero the NB_PAD-alignment pad columns so scan's int4 reduce is exact
        for (int x = tid; x < N_REL * (NB_PAD - NB_CHUNK); x += 256) {
            int r = x / (NB_PAD - NB_CHUNK), p = x % (NB_PAD - NB_CHUNK);
            blockCountsT[r * NB_PAD + NB_CHUNK + p] = 0;
        }
    } else if (b < HIST_BASE) {
        int base = (b - (N_REL + 1)) * 1024 + tid * 4;
        if (base + 3 < OUT_ELEMS)
            *(float4*)(out + base) = make_float4(0.f, 0.f, 0.f, 0.f);
        else
            for (int k = 0; k < 4; k++)
                if (base + k < OUT_ELEMS) out[base + k] = 0.f;
    } else {
        __shared__ int h[N_REL];
        int c = b - HIST_BASE;               // chunk id, 0..240
        for (int x = tid; x < N_REL; x += 256) h[x] = 0;
        __syncthreads();
        int e0 = c * CHUNK;
        int e1 = e0 + CHUNK; if (e1 > N_EDGES) e1 = N_EDGES;
        for (int e = e0 + tid; e < e1; e += 256) {
            int r = rel[e]; r = r < 0 ? 0 : (r >= N_REL ? N_REL - 1 : r);
            atomicAdd(&h[r], 1);
        }
        __syncthreads();
        for (int x = tid; x < N_REL; x += 256)
            blockCountsT[x * NB_PAD + c] = h[x];
    }
}

// Dispatch 2 — mega: scan(block 0) || gate(all) -> scanflag-wait -> scatter
// / dummy-writers -> software grid barrier -> edge. 256 blocks = 1/CU, so
// all blocks are co-resident and the spin barrier cannot deadlock; all
// cross-block signaling uses device-scope atomics + __threadfence (G16).
__global__ __launch_bounds__(256, 2) void mega_kernel(
    const float* __restrict__ node_feat,  // [N,32]
    const float* __restrict__ ttr,        // [E,32]
    const float* __restrict__ tre,        // [E,32]
    const float* __restrict__ Ab,         // [32]
    const float* __restrict__ Bw,         // [1,32]
    const float* __restrict__ Bb,         // [1]
    const int*  __restrict__ edge0,       // [E]
    const int*  __restrict__ edge1,       // [E]
    const int*  __restrict__ rel,         // [E]
    const unsigned short* __restrict__ aw_bf,
    const unsigned short* __restrict__ relwT_bf,
    const unsigned short* __restrict__ slwT_bf,
    const int* __restrict__ blockCountsT,
    int* __restrict__ blockBaseT,
    int* __restrict__ offs, int* __restrict__ tots,
    int* __restrict__ flags,
    int4* __restrict__ slot4,
    float* __restrict__ out)              // [N,32] fp32 (pre-zeroed)
{
    int b = blockIdx.x, tid = threadIdx.x;
    int wave = tid >> 6;
    int lane = tid & 63;
    int m = lane & 15;          // edge row within group / out col
    int q = lane >> 4;          // k-chunk / row-group

    __shared__ float a_stash[CHUNK];      // this block's gate values
    __shared__ int   cur[N_REL];
    __shared__ int   s0[256];
    __shared__ int   pval[256];

    int* scanflag = flags;
    int* bar      = flags + 1;

    // ---------------- Phase 1: scan (block 0 only) -------------------------
    if (b == 0) {
        int tot = 0;
        if (tid < N_REL) {
            const int4* cp = (const int4*)(blockCountsT + tid * NB_PAD);
            for (int c = 0; c < NB_PAD / 4; c++) {
                int4 v = cp[c];
                tot += v.x + v.y + v.z + v.w;
            }
        }
        int p = (tid < N_REL) ? ((tot + 15) & ~15) : 0;
        pval[tid] = p;
        s0[tid] = p;
        __syncthreads();
        #pragma unroll
        for (int d = 1; d < 256; d <<= 1) {
            int v = s0[tid];
            if (tid >= d) v += s0[tid - d];
            __syncthreads();
            s0[tid] = v;
            __syncthreads();
        }
        int off = s0[tid] - pval[tid];
        if (tid < N_REL) { offs[tid] = off; tots[tid] = tot; }
        if (tid == 255) offs[N_REL] = s0[255];
        if (tid < N_REL) {
            const int4* cp = (const int4*)(blockCountsT + tid * NB_PAD);
            int4* bp = (int4*)(blockBaseT + tid * NB_PAD);
            int run = off;
            for (int c = 0; c < NB_PAD / 4; c++) {
                int4 v = cp[c];
                int4 w;
                w.x = run;
                w.y = w.x + v.x;
                w.z = w.y + v.y;
                w.w = w.z + v.z;
                run = w.w + v.w;
                bp[c] = w;
            }
        }
        __syncthreads();
        if (tid == 0) {
            __threadfence();
            __hip_atomic_store(scanflag, 1, __ATOMIC_RELEASE, __HIP_MEMORY_SCOPE_AGENT);
        }
    }

    // ---------------- Phase 2: gate own chunk (stash a in LDS) -------------
    int g_lo = b * CPG;
    int g_cnt = 0;
    if (b < NB_CHUNK) {
        g_cnt = NGROUPS - g_lo; if (g_cnt > CPG) g_cnt = CPG;

        short8 bA[4][2];
        #pragma unroll
        for (int hh = 0; hh < 2; hh++)
            #pragma unroll
            for (int c = 0; c < 4; c++)
                bA[c][hh] = *(const short8*)(aw_bf + (16 * hh + m) * 128 + 32 * c + 8 * q);
        float ab0 = Ab[m], ab1 = Ab[16 + m];
        float bw0 = Bw[m], bw1 = Bw[16 + m], Bb0 = Bb[0];

        for (int gi = wave; gi < g_cnt; gi += 4) {
            int ebase = (g_lo + gi) * 64;        // always fully in-bounds
            int e_lane = ebase + lane;
            int s_ld = edge0[e_lane]; s_ld = s_ld < 0 ? 0 : (s_ld >= N_NODES ? N_NODES - 1 : s_ld);
            int t_ld = edge1[e_lane]; t_ld = t_ld < 0 ? 0 : (t_ld >= N_NODES ? N_NODES - 1 : t_ld);

            short8 fsrc[4], ftgt[4], fre_[4], ftr_[4];
            #pragma unroll
            for (int g = 0; g < 4; g++) {
                int s_m = __shfl(s_ld, g * 16 + m, 64);
                int t_m = __shfl(t_ld, g * 16 + m, 64);
                int e_m = ebase + g * 16 + m;
                const float* sp = node_feat + s_m * DIM + q * 8;
                float4 sv0 = *(const float4*)sp, sv1 = *(const float4*)(sp + 4);
                const float* tp = node_feat + t_m * DIM + q * 8;
                float4 tv0 = *(const float4*)tp, tv1 = *(const float4*)(tp + 4);
                const float* rp = tre + e_m * DIM + q * 8;   // coalesced
                float4 rv0 = *(const float4*)rp, rv1 = *(const float4*)(rp + 4);
                const float* qp = ttr + e_m * DIM + q * 8;   // coalesced
                float4 qv0 = *(const float4*)qp, qv1 = *(const float4*)(qp + 4);
                fsrc[g] = cvt8(sv0, sv1);
                ftgt[g] = cvt8(tv0, tv1);
                fre_[g] = cvt8(rv0, rv1);
                ftr_[g] = cvt8(qv0, qv1);
            }

            #pragma unroll
            for (int g = 0; g < 4; g++) {
                f32x4 h0 = {ab0, ab0, ab0, ab0};
                f32x4 h1 = {ab1, ab1, ab1, ab1};
                h0 = MFMA(fsrc[g], bA[0][0], h0);  h1 = MFMA(fsrc[g], bA[0][1], h1);
                h0 = MFMA(ftgt[g], bA[1][0], h0);  h1 = MFMA(ftgt[g], bA[1][1], h1);
                h0 = MFMA(fre_[g], bA[2][0], h0);  h1 = MFMA(fre_[g], bA[2][1], h1);
                h0 = MFMA(ftr_[g], bA[3][0], h0);  h1 = MFMA(ftr_[g], bA[3][1], h1);

                float av[4];
                #pragma unroll
                for (int v = 0; v < 4; v++) {
                    float p = fmaxf(h0[v], 0.f) * bw0 + fmaxf(h1[v], 0.f) * bw1;
                    p += __shfl_xor(p, 1, 16);
                    p += __shfl_xor(p, 2, 16);
                    p += __shfl_xor(p, 4, 16);
                    p += __shfl_xor(p, 8, 16);
                    av[v] = 1.f / (1.f + __expf(-(p + Bb0)));
                }
                // lanes (q, m<4) own edge j = g*16 + 4q + m with gate av[m]
                float a_j = (m == 0) ? av[0] : (m == 1) ? av[1]
                          : (m == 2) ? av[2] : av[3];
                if (m < 4) a_stash[gi * 64 + g * 16 + 4 * q + m] = a_j;
            }
        }
    }

    // ---------------- wait for scan (already done under gate) --------------
    __syncthreads();
    if (tid == 0)
        while (__hip_atomic_load(scanflag, __ATOMIC_ACQUIRE, __HIP_MEMORY_SCOPE_AGENT) == 0)
            __builtin_amdgcn_s_sleep(2);
    __syncthreads();
    __threadfence();

    // ---------------- Phase 3: scatter own chunk / write dummies -----------
    if (b < NB_CHUNK) {
        for (int x = tid; x < N_REL; x += 256)
            cur[x] = blockBaseT[x * NB_PAD + b];
        __syncthreads();
        int c0 = g_lo * 64;
        int clen = g_cnt * 64;
        for (int ei = tid; ei < clen; ei += 256) {
            int e = c0 + ei;
            int r = rel[e];   r = r < 0 ? 0 : (r >= N_REL   ? N_REL   - 1 : r);
            int s = edge0[e]; s = s < 0 ? 0 : (s >= N_NODES ? N_NODES - 1 : s);
            int t = edge1[e]; t = t < 0 ? 0 : (t >= N_NODES ? N_NODES - 1 : t);
            int pos = atomicAdd(&cur[r], 1);
            slot4[pos] = make_int4(s, t, __float_as_int(a_stash[ei]), r);
        }
    } else {
        int db = b - NB_CHUNK;               // 0..14
        const int4 dummy = make_int4(0, -1, 0, 0);
        for (int r = db; r < N_REL; r += N_DUMMY_WRITERS) {
            int start = offs[r] + tots[r];
            int end   = offs[r] + ((tots[r] + 15) & ~15);
            for (int j = start + tid; j < end; j += 256)
                slot4[j] = dummy;
        }
        int padTotal = offs[N_REL];
        for (int j = padTotal + db * 256 + tid; j < PE_MAX; j += N_DUMMY_WRITERS * 256)
            slot4[j] = dummy;
    }

    // ---------------- software grid barrier --------------------------------
    __syncthreads();
    if (tid == 0) {
        __threadfence();
        __hip_atomic_fetch_add(bar, 1, __ATOMIC_ACQ_REL, __HIP_MEMORY_SCOPE_AGENT);
        while (__hip_atomic_load(bar, __ATOMIC_ACQUIRE, __HIP_MEMORY_SCOPE_AGENT) < MEGA_BLK)
            __builtin_amdgcn_s_sleep(2);
    }
    __syncthreads();
    __threadfence();

    // ---------------- Phase 4: edge (msg + self-loop MFMAs, gated atomics) -
    short8 bS[2];
    bS[0] = *(const short8*)(slwT_bf + m * 32 + 8 * q);
    bS[1] = *(const short8*)(slwT_bf + (16 + m) * 32 + 8 * q);

    for (int u = b * 4 + wave; u < EDGE_UNITS; u += MEGA_BLK * 4) {
        int wbase = u * 64;
        int4 v = slot4[wbase + lane];               // coalesced
        int s_ld = v.x, t_ld = v.y, a_ld = v.z, r_ld = v.w;

        short8 fsrc[4], ftgt[4], bM[4][2];
        #pragma unroll
        for (int g = 0; g < 4; g++) {
            int r_g = __shfl(r_ld, g * 16, 64);     // uniform within group
            int s_m = __shfl(s_ld, g * 16 + m, 64);
            int t_m = __shfl(t_ld, g * 16 + m, 64);
            int t_mc = t_m < 0 ? 0 : t_m;
            const float* sp = node_feat + s_m * DIM + q * 8;
            float4 sv0 = *(const float4*)sp, sv1 = *(const float4*)(sp + 4);
            const float* tp = node_feat + t_mc * DIM + q * 8;
            float4 tv0 = *(const float4*)tp, tv1 = *(const float4*)(tp + 4);
            fsrc[g] = cvt8(sv0, sv1);
            ftgt[g] = cvt8(tv0, tv1);
            bM[g][0] = *(const short8*)(relwT_bf + r_g * 1024 + m * 32 + 8 * q);
            bM[g][1] = *(const short8*)(relwT_bf + r_g * 1024 + (16 + m) * 32 + 8 * q);
        }

        #pragma unroll
        for (int g = 0; g < 4; g++) {
            f32x4 m0 = {0.f, 0.f, 0.f, 0.f};
            f32x4 m1 = {0.f, 0.f, 0.f, 0.f};
            f32x4 c0 = {0.f, 0.f, 0.f, 0.f};
            f32x4 c1 = {0.f, 0.f, 0.f, 0.f};
            m0 = MFMA(fsrc[g], bM[g][0], m0);
            m1 = MFMA(fsrc[g], bM[g][1], m1);
            c0 = MFMA(ftgt[g], bS[0], c0);
            c1 = MFMA(ftgt[g], bS[1], c1);
            #pragma unroll
            for (int vv = 0; vv < 4; vv++) {
                int row = 4 * q + vv;
                int tv = __shfl(t_ld, g * 16 + row, 64);
                float a_row = __int_as_float(__shfl(a_ld, g * 16 + row, 64));
                if (tv >= 0) {
                    atomicAdd(&out[tv * DIM + m],      c0[vv] + m0[vv] * a_row);
                    atomicAdd(&out[tv * DIM + 16 + m], c1[vv] + m1[vv] * a_row);
                }
            }
        }
    }
}

extern "C" void kernel_launch(void* const* d_in, const int* in_sizes, int n_in,
                              void* d_out, int out_size, void* d_ws, size_t ws_size,
                              hipStream_t stream) {
    const float* node_feat = (const float*)d_in[0];
    const float* ttr       = (const float*)d_in[1];
    const float* tre       = (const float*)d_in[2];
    const float* weight    = (const float*)d_in[3];
    const float* w_comp    = (const float*)d_in[4];
    const float* slw       = (const float*)d_in[5];
    const float* Aw        = (const float*)d_in[6];
    const float* Ab        = (const float*)d_in[7];
    const float* Bw        = (const float*)d_in[8];
    const float* Bb        = (const float*)d_in[9];
    const int*  total_edge = (const int*)d_in[10];
    const int*  rel        = (const int*)d_in[11];
    const int*  edge0 = total_edge;
    const int*  edge1 = total_edge + N_EDGES;

    char* ws = (char*)d_ws;
    unsigned short* relwT_bf = (unsigned short*)ws;
    unsigned short* aw_bf    = (unsigned short*)(ws + AWBF_OFF);
    unsigned short* slwT_bf  = (unsigned short*)(ws + SLWT_OFF);
    int*  blockCountsT = (int*)(ws + BCT_OFF);
    int*  blockBaseT   = (int*)(ws + BBT_OFF);
    int*  offs         = (int*)(ws + OFFS_OFF);
    int*  tots         = (int*)(ws + TOTS_OFF);
    int*  flags        = (int*)(ws + FLAG_OFF);
    int4* slot4        = (int4*)(ws + SLOT_OFF);
    float* out = (float*)d_out;

    prep_kernel<<<PREP_BLOCKS, 256, 0, stream>>>(
        weight, w_comp, Aw, slw, rel, relwT_bf, aw_bf, slwT_bf,
        blockCountsT, flags, out);

    mega_kernel<<<MEGA_BLK, 256, 0, stream>>>(
        node_feat, ttr, tre, Ab, Bw, Bb, edge0, edge1, rel,
        aw_bf, relwT_bf, slwT_bf, blockCountsT, blockBaseT,
        offs, tots, flags, slot4, out);
}